// Round 11
// baseline (121.662 us; speedup 1.0000x reference)
//
#include <hip/hip_runtime.h>

// Problem constants: B=32, C_IN=64, C_OUT=128, K=3, H=W=128
#define BATCH 32
#define CIN   64
#define COUT  128
#define HW    128
#define OW    126            // H-K+1
#define IMG4  508032         // float4s per batch-image of out (128*126*126/4)
#define WTN   (32 * 576 * 4) // repacked weight floats: [ocGroup4][ic*9+t][4]

typedef float f4 __attribute__((ext_vector_type(4)));

// ---- Kernel 1: xs[c,h,w] = sum_b x[b,c,h,w]; f4, 4 chains, nt loads.
// Blocks 0..287 additionally repack w -> wt (for conv's scalar weight loads).
__global__ __launch_bounds__(256) void k_bsum(const float* __restrict__ x,
                                              float* __restrict__ xs,
                                              const float* __restrict__ w,
                                              float* __restrict__ wt) {
    const int i = blockIdx.x * blockDim.x + threadIdx.x;   // over 262144 f4s
    const f4* __restrict__ x4 = (const f4*)x;
    const size_t s4 = CIN * HW * HW / 4;                   // 262144 f4 per batch
    f4 a0 = __builtin_nontemporal_load(&x4[i]);
    f4 a1 = __builtin_nontemporal_load(&x4[s4 + i]);
    f4 a2 = __builtin_nontemporal_load(&x4[2 * s4 + i]);
    f4 a3 = __builtin_nontemporal_load(&x4[3 * s4 + i]);
    #pragma unroll
    for (int b = 4; b < BATCH; b += 4) {
        a0 += __builtin_nontemporal_load(&x4[(size_t)b * s4 + i]);
        a1 += __builtin_nontemporal_load(&x4[(size_t)(b + 1) * s4 + i]);
        a2 += __builtin_nontemporal_load(&x4[(size_t)(b + 2) * s4 + i]);
        a3 += __builtin_nontemporal_load(&x4[(size_t)(b + 3) * s4 + i]);
    }
    ((f4*)xs)[i] = (a0 + a1) + (a2 + a3);

    // Weight repack: wt[g*2304 + r*4 + o] = w[(g*4+o)*576 + r]
    if (blockIdx.x < WTN / 256) {
        const int idx = blockIdx.x * 256 + threadIdx.x;
        const int o = idx & 3;
        const int r = (idx >> 2) % 576;
        const int g = idx / 2304;
        wt[idx] = w[(g * 4 + o) * 576 + r];
    }
}

// ---- Kernel 2: conv(xs, wt) + bias -> out batch 0 ONLY ----
// No LDS, no barriers. Weights are wave-uniform -> pointer built from
// readfirstlane -> compiler emits s_load (scalar pipe), freeing LDS/VALU.
// x direct from global/L2 with double-buffered register prefetch.
// Tile: 8 rows x 32 cols x 16 oc. Grid (64 spatial, 8 ocg) = 512 blocks, 2/CU.
#define OCT 16             // out channels per block

__global__ __launch_bounds__(256, 2) void k_conv(const float* __restrict__ xs,
                                                 const float* __restrict__ wt,
                                                 const float* __restrict__ bias,
                                                 float* __restrict__ out) {
    const int tid  = threadIdx.x;
    const int tile = blockIdx.x;                 // 0..63
    const int ocg  = blockIdx.y;                 // 0..7
    const int row0 = (tile >> 2) * 8;            // 0..120
    const int col0 = (tile & 3) * 32;            // 0,32,64,96
    const int oc0  = ocg * OCT;

    const int tx = tid & 7;
    const int ty = (tid >> 3) & 7;
    const int og = tid >> 6;                     // 0..3 (wave-uniform)

    const int irow = row0 + ty;                  // output row; input rows irow+ky
    const int icol = col0 + tx * 4;              // output col base
    const bool tail = (icol + 5) < HW;           // cols icol+4..5 loadable

    // Uniform weight base for this wave's 4 output channels
    const int ogl = __builtin_amdgcn_readfirstlane(ocg * 4 + og);
    const float* __restrict__ wp = wt + (size_t)ogl * 2304;  // [ic*9+t][4]

    float acc[4][4] = {};                        // [oc][px]

    float bufA[18], bufB[18];                    // x values, [ky*6 + j]
    const float* xbase = &xs[(size_t)irow * HW + icol];

    auto loadx = [&](float* buf, int ic) {
        const float* p = xbase + (size_t)ic * (HW * HW);
        #pragma unroll
        for (int ky = 0; ky < 3; ++ky) {
            const int gr = irow + ky;
            if (gr < HW) {
                const float4 xa = *(const float4*)(p + ky * HW);
                buf[ky * 6 + 0] = xa.x; buf[ky * 6 + 1] = xa.y;
                buf[ky * 6 + 2] = xa.z; buf[ky * 6 + 3] = xa.w;
                if (tail) {
                    const float2 xt = *(const float2*)(p + ky * HW + 4);
                    buf[ky * 6 + 4] = xt.x; buf[ky * 6 + 5] = xt.y;
                } else { buf[ky * 6 + 4] = 0.f; buf[ky * 6 + 5] = 0.f; }
            } else {
                #pragma unroll
                for (int j = 0; j < 6; ++j) buf[ky * 6 + j] = 0.f;
            }
        }
    };

    auto fmas = [&](const float* buf, int ic) {
        #pragma unroll
        for (int ky = 0; ky < 3; ++ky) {
            #pragma unroll
            for (int kx = 0; kx < 3; ++kx) {
                // uniform address -> s_load_dwordx4 into SGPRs
                const f4 wv = *(const f4*)(wp + (ic * 9 + ky * 3 + kx) * 4);
                const float wf[4] = {wv.x, wv.y, wv.z, wv.w};
                #pragma unroll
                for (int o = 0; o < 4; ++o)
                    #pragma unroll
                    for (int p = 0; p < 4; ++p)
                        acc[o][p] = fmaf(wf[o], buf[ky * 6 + kx + p], acc[o][p]);
            }
        }
    };

    loadx(bufA, 0);
    for (int ic = 0; ic < CIN; ic += 2) {        // software pipeline, depth 1
        loadx(bufB, ic + 1);
        fmas(bufA, ic);
        if (ic + 2 < CIN) loadx(bufA, ic + 2);
        fmas(bufB, ic + 1);
    }

    // Bias + write batch 0 only (row pitch 126f -> float2 stores)
    if (irow < OW) {
        #pragma unroll
        for (int o = 0; o < 4; ++o) {
            const int oc = oc0 + og * 4 + o;
            const float bv = bias[oc];
            const float r0 = acc[o][0] + bv, r1 = acc[o][1] + bv;
            const float r2 = acc[o][2] + bv, r3 = acc[o][3] + bv;
            float* op = &out[((size_t)oc * OW + irow) * OW + icol];
            if (icol + 4 <= OW) {
                ((float2*)op)[0] = make_float2(r0, r1);
                ((float2*)op)[1] = make_float2(r2, r3);
            } else {                              // icol == 124: 2 cols left
                ((float2*)op)[0] = make_float2(r0, r1);
            }
        }
    }
}

// ---- Kernel 3: broadcast out[0] -> out[1..31] (exact R6) ----
__global__ __launch_bounds__(256) void k_bcast(float* __restrict__ out) {
    f4* __restrict__ o4 = (f4*)out;
    const int r0 = blockIdx.x * 512 + threadIdx.x;
    const int r1 = r0 + 256;
    const bool ok0 = r0 < IMG4;
    const bool ok1 = r1 < IMG4;
    f4 v0 = {}; f4 v1 = {};
    if (ok0) v0 = o4[r0];
    if (ok1) v1 = o4[r1];
    #pragma unroll
    for (int b = 1; b < BATCH; ++b) {
        const size_t base = (size_t)b * IMG4;
        if (ok0) o4[base + r0] = v0;
        if (ok1) o4[base + r1] = v1;
    }
}

extern "C" void kernel_launch(void* const* d_in, const int* in_sizes, int n_in,
                              void* d_out, int out_size, void* d_ws, size_t ws_size,
                              hipStream_t stream) {
    const float* x    = (const float*)d_in[0];   // [32,64,128,128]
    const float* w    = (const float*)d_in[1];   // [128,64,3,3]
    const float* bias = (const float*)d_in[2];   // [128,1,1]
    float* out = (float*)d_out;                  // [32,128,126,126]
    float* wt  = (float*)d_ws;                   // repacked weights (288 KB)
    float* xs  = wt + WTN;                       // [64,128,128] (4 MB), 16B-aligned

    k_bsum<<<dim3(CIN * HW * HW / 4 / 256), dim3(256), 0, stream>>>(x, xs, w, wt);
    k_conv<<<dim3(64, 8), dim3(256), 0, stream>>>(xs, wt, bias, out);
    k_bcast<<<dim3((IMG4 + 511) / 512), dim3(256), 0, stream>>>(out);
}